// Round 5
// baseline (891.560 us; speedup 1.0000x reference)
//
#include <hip/hip_runtime.h>
#include <hip/hip_bf16.h>

// SDEnet R5: 256x256 8-phase GEMM with one-phase-ahead FRAGMENT prefetch (counted lgkmcnt
// via compiler), counted vmcnt(8) steady-state, peeled last 2 K-tiles. T1+T2+T3+T4+T5.
// (R4 compile fix: PHASE is variadic; prefetch statements passed as __VA_ARGS__.)

typedef unsigned short u16;
typedef __attribute__((ext_vector_type(8))) short short8;
typedef __attribute__((ext_vector_type(8))) u16 u16x8;
typedef __attribute__((ext_vector_type(4))) u16 u16x4;
typedef __attribute__((ext_vector_type(4))) float f32x4;

#define BROWS 32768
#define DDIM 1024
#define NBLK 5
#define H_STEP 0.1f
#define SQRT_H 0.31622776601683794f

#define FENCE() asm volatile("" ::: "memory")
#define BARRIER() do { FENCE(); __builtin_amdgcn_s_barrier(); FENCE(); } while (0)

__device__ __forceinline__ float bf2f(u16 u) {
    return __uint_as_float(((unsigned)u) << 16);
}
__device__ __forceinline__ u16 f2bf(float f) {
    unsigned u = __float_as_uint(f);
    unsigned r = 0x7fffu + ((u >> 16) & 1u);
    return (u16)((u + r) >> 16);
}
__device__ __forceinline__ float fast_tanh(float s) {
    float e = __expf(2.0f * s);
    return 1.0f - 2.0f * __builtin_amdgcn_rcpf(e + 1.0f);
}

// async global -> LDS, 16B per lane, wave-uniform LDS base + lane*16
#define GLOAD_LDS16(g, l)                                                        \
    __builtin_amdgcn_global_load_lds(                                            \
        (const __attribute__((address_space(1))) unsigned int*)(const void*)(g), \
        (__attribute__((address_space(3))) unsigned int*)(void*)(l), 16, 0, 0)

// ---------------- pad/convert fp32 -> bf16 (optionally zero-padded cols) ----------------
__global__ __launch_bounds__(256) void pad_cvt(const float* __restrict__ src,
                                               u16* __restrict__ dst,
                                               int R, int C, int Cp) {
    int idx = blockIdx.x * 256 + threadIdx.x;
    if (idx >= R * Cp) return;
    int r = idx / Cp;
    int c = idx - r * Cp;
    float v = (c < C) ? src[(size_t)r * C + c] : 0.0f;
    dst[idx] = f2bf(v);
}

// ---------------- zw[i][b] = sum_d noise[i][b][d] * bw[i][d]  (one wave per row) --------
__global__ __launch_bounds__(256) void zw_kernel(const float* __restrict__ noise,
                                                 const float* __restrict__ bw,
                                                 float* __restrict__ zw) {
    int gw = (blockIdx.x * 256 + threadIdx.x) >> 6;
    int lane = threadIdx.x & 63;
    if (gw >= NBLK * BROWS) return;
    int i = gw >> 15;
    const float* zr = noise + (size_t)gw * DDIM;
    const float* wr = bw + i * DDIM;
    float s = 0.0f;
#pragma unroll
    for (int it = 0; it < 4; ++it) {
        int k = it * 256 + lane * 4;
        f32x4 z = *(const f32x4*)(zr + k);
        f32x4 w = *(const f32x4*)(wr + k);
        s += z.x * w.x + z.y * w.y + z.z * w.z + z.w * w.w;
    }
#pragma unroll
    for (int off = 32; off > 0; off >>= 1) s += __shfl_down(s, off, 64);
    if (lane == 0) zw[gw] = s;
}

// ---------------- 256^2 8-phase GEMM: C = A[M][KK] @ B[1024][KK]^T ----------------------
// LDS per buf(65536B): A:[kh(16384)][row256][k32 bf16], B at +32768 same. 2 bufs = 128 KiB.
// Chunk swizzle (both sides): physical 16B-chunk = logical ^ ((row>>1)&3).
template <int KK, int EPI>
__global__ __launch_bounds__(512, 2) void gemm256(const u16* __restrict__ Ag,
                                                  const u16* __restrict__ Bg,
                                                  const float* __restrict__ bias,
                                                  u16* __restrict__ outW,
                                                  const u16* __restrict__ outR,
                                                  const float* __restrict__ zw,
                                                  const float* __restrict__ bwv) {
    constexpr int NT = KK / 64;
    static_assert(NT >= 2 && (NT & 1) == 0, "NT even, >=2");
    __shared__ __align__(16) u16 smem[65536];  // 128 KiB
    char* lds = (char*)smem;

    const int bid = blockIdx.x;                 // 512 blocks, 512 % 8 == 0
    const int swz = (bid & 7) * 64 + (bid >> 3);
    const int row0 = (swz >> 2) * 256;
    const int col0 = (swz & 3) * 256;

    const int tid = threadIdx.x;
    const int lane = tid & 63;
    const int wid = tid >> 6;
    const int wm = wid >> 2;   // 2 row-waves
    const int wn = wid & 3;    // 4 col-waves

    // ---- staging: thread covers row (tid>>2)(+128), logical chunk (tid&3), pre-swizzled
    const int srow = tid >> 2;
    const int skq = (tid & 3) ^ ((tid >> 3) & 3);   // ^((row>>1)&3)
    const u16* agp0 = Ag + (size_t)(row0 + srow) * KK + skq * 8;
    const u16* agp1 = Ag + (size_t)(row0 + 128 + srow) * KK + skq * 8;
    const u16* bgp0 = Bg + (size_t)(col0 + srow) * KK + skq * 8;
    const u16* bgp1 = Bg + (size_t)(col0 + 128 + srow) * KK + skq * 8;
    char* lp0 = lds + wid * 1024;  // wave-uniform LDS base (+lane*16 by HW)

    // stage half: 0=A-kh0, 1=B-kh0, 2=A-kh1, 3=B-kh1 of tile t -> buf[t&1]
    auto stage = [&](int t, int half) {
        const int is_b = half & 1;
        const int kh = half >> 1;
        const int koff = t * 64 + kh * 32;
        char* dst = lp0 + ((t & 1) << 16) + (is_b << 15) + (kh << 14);
        const u16* g0 = (is_b ? bgp0 : agp0) + koff;
        const u16* g1 = (is_b ? bgp1 : agp1) + koff;
        GLOAD_LDS16(g0, dst);
        GLOAD_LDS16(g1, dst + 8192);
    };

    // ---- frag-read bases: logical chunk = lane>>4, row ~ lane&15 -> phys ^ ((lane>>1)&3)
    const int rchunk = ((lane >> 4) ^ ((lane >> 1) & 3)) << 4;
    const int aoff = (wm * 128 + (lane & 15)) * 64 + rchunk;          // + m*1024 + kh*16384 + buf*65536
    const int boff = 32768 + (wn * 64 + (lane & 15)) * 64 + rchunk;   // + (hn*2+i)*1024 + ...

    short8 afP[8], afQ[8], bfP[2], bfQ[2];
    f32x4 acc[8][4];
#pragma unroll
    for (int m = 0; m < 8; ++m)
#pragma unroll
        for (int n = 0; n < 4; ++n) acc[m][n] = (f32x4){0.f, 0.f, 0.f, 0.f};

#define PF_A(dst, kh, bufc)                                                           \
    do {                                                                              \
        _Pragma("unroll") for (int m = 0; m < 8; ++m)                                 \
            dst[m] = *(const short8*)(lds + aoff + m * 1024 + (kh) * 16384 + (bufc) * 65536); \
    } while (0)
#define PF_B(dst, kh, hn, bufc)                                                       \
    do {                                                                              \
        dst[0] = *(const short8*)(lds + boff + ((hn) * 2 + 0) * 1024 + (kh) * 16384 + (bufc) * 65536); \
        dst[1] = *(const short8*)(lds + boff + ((hn) * 2 + 1) * 1024 + (kh) * 16384 + (bufc) * 65536); \
    } while (0)
#define MFMA16(af, bf, hn)                                                            \
    do {                                                                              \
        _Pragma("unroll") for (int m = 0; m < 8; ++m) {                               \
            acc[m][(hn) * 2 + 0] = __builtin_amdgcn_mfma_f32_16x16x32_bf16(af[m], bf[0], acc[m][(hn) * 2 + 0], 0, 0, 0); \
            acc[m][(hn) * 2 + 1] = __builtin_amdgcn_mfma_f32_16x16x32_bf16(af[m], bf[1], acc[m][(hn) * 2 + 1], 0, 0, 0); \
        }                                                                             \
    } while (0)
// phase: prefetch (VA_ARGS) next quadrant's frags, issue stage, barrier, MFMA this quadrant.
// Compiler emits COUNTED lgkmcnt before MFMA (consumed frags are older than the prefetches).
#define PHASE(STG, af, bf, hn, VMW, ...)                                              \
    do {                                                                              \
        __VA_ARGS__;                                                                  \
        STG;                                                                          \
        FENCE(); __builtin_amdgcn_s_barrier(); FENCE();                               \
        __builtin_amdgcn_s_setprio(1);                                                \
        MFMA16(af, bf, hn);                                                           \
        __builtin_amdgcn_s_setprio(0);                                                \
        VMW;                                                                          \
        FENCE(); __builtin_amdgcn_s_barrier(); FENCE();                               \
    } while (0)
#define VM8 asm volatile("s_waitcnt vmcnt(8)" ::: "memory")
#define VM4 asm volatile("s_waitcnt vmcnt(4)" ::: "memory")
#define VM0 asm volatile("s_waitcnt vmcnt(0)" ::: "memory")
#define NOSTG ((void)0)
#define NOVM ((void)0)
#define NOPREF ((void)0)

// full tile kt (buf c), stages valid (kt+2 <= NT-1):
#define TILE_FULL(kt, c)                                                              \
    do {                                                                              \
        PHASE(stage((kt) + 1, 3), afP, bfP, 0, VM8, PF_B(bfQ, 0, 1, c));              \
        PHASE(stage((kt) + 2, 0), afP, bfQ, 1, NOVM, PF_A(afQ, 1, c); PF_B(bfP, 1, 0, c)); \
        PHASE(stage((kt) + 2, 1), afQ, bfP, 0, VM8, PF_B(bfQ, 1, 1, c));              \
        PHASE(stage((kt) + 2, 2), afQ, bfQ, 1, NOVM, PF_A(afP, 0, (c) ^ 1); PF_B(bfP, 0, 0, (c) ^ 1)); \
    } while (0)

    // ---- prologue: tile0 all + tile1 halves 0..2 (14 loads); prefetch tile0 q0 frags
    stage(0, 0); stage(0, 1); stage(0, 2); stage(0, 3);
    stage(1, 0); stage(1, 1); stage(1, 2);
    asm volatile("s_waitcnt vmcnt(10)" ::: "memory");  // (0,0),(0,1) landed
    BARRIER();
    PF_A(afP, 0, 0);
    PF_B(bfP, 0, 0, 0);

    for (int kt2 = 0; kt2 < NT / 2 - 1; ++kt2) {
        const int kt = 2 * kt2;
        TILE_FULL(kt, 0);
        TILE_FULL(kt + 1, 1);
    }
    // ---- peeled tile NT-2 (buf 0): only stage(NT-1,3) remains
    PHASE(stage(NT - 1, 3), afP, bfP, 0, VM8, PF_B(bfQ, 0, 1, 0));
    PHASE(NOSTG, afP, bfQ, 1, NOVM, PF_A(afQ, 1, 0); PF_B(bfP, 1, 0, 0));
    PHASE(NOSTG, afQ, bfP, 0, VM4, PF_B(bfQ, 1, 1, 0));
    PHASE(NOSTG, afQ, bfQ, 1, NOVM, PF_A(afP, 0, 1); PF_B(bfP, 0, 0, 1));
    // ---- peeled tile NT-1 (buf 1): no stages; vmcnt(0) then pure pipeline
    PHASE(NOSTG, afP, bfP, 0, VM0, PF_B(bfQ, 0, 1, 1));
    PHASE(NOSTG, afP, bfQ, 1, NOVM, PF_A(afQ, 1, 1); PF_B(bfP, 1, 0, 1));
    PHASE(NOSTG, afQ, bfP, 0, NOVM, PF_B(bfQ, 1, 1, 1));
    PHASE(NOSTG, afQ, bfQ, 1, NOVM, NOPREF);

    // ---- epilogue: all LDS reads drained (last phase lgkm) + final barrier passed ----
    float bcol[4];
#pragma unroll
    for (int ng = 0; ng < 4; ++ng) bcol[ng] = bias[col0 + wn * 64 + ng * 16 + (lane & 15)];

    char* wbase = lds + wid * 16384;  // wave-private 128x64 bf16 delta tile
    const int lr0 = (lane >> 4) * 4;
    const int lc0 = lane & 15;
#pragma unroll
    for (int m = 0; m < 8; ++m) {
#pragma unroll
        for (int ng = 0; ng < 4; ++ng) {
#pragma unroll
            for (int j = 0; j < 4; ++j) {
                int lrow = m * 16 + lr0 + j;
                int lcol = ng * 16 + lc0;
                float t = fast_tanh(acc[m][ng][j] + bcol[ng]);
                float d = (EPI == 0) ? t : H_STEP * t;
                int chunk = (lcol >> 3) ^ ((lrow >> 2) & 7);
                *(u16*)(wbase + lrow * 128 + (chunk << 4) + (lcol & 7) * 2) = f2bf(d);
            }
        }
    }

    const int gr_base = row0 + wm * 128;
    const int gc_base = col0 + wn * 64;
#pragma unroll
    for (int it = 0; it < 16; ++it) {
        int lrow = it * 8 + (lane >> 3);
        int chunk = lane & 7;
        int schunk = chunk ^ ((lrow >> 2) & 7);
        u16x8 d8 = *(const u16x8*)(wbase + lrow * 128 + (schunk << 4));
        int grow = gr_base + lrow;
        int gcol = gc_base + chunk * 8;
        size_t gidx = (size_t)grow * DDIM + gcol;
        u16x8 o8;
        if constexpr (EPI == 0) {
            o8 = d8;
        } else {
            u16x8 old8 = *(const u16x8*)(outR + gidx);
            float zr = SQRT_H * zw[grow];
            f32x4 bw0 = *(const f32x4*)(bwv + gcol);
            f32x4 bw1 = *(const f32x4*)(bwv + gcol + 4);
#pragma unroll
            for (int e = 0; e < 8; ++e) {
                float bwe = (e < 4) ? bw0[e] : bw1[e - 4];
                float v = bf2f(old8[e]) + bf2f(d8[e]) + zr * bwe;
                o8[e] = f2bf(v);
            }
        }
        *(u16x8*)(outW + gidx) = o8;
    }
#undef PF_A
#undef PF_B
#undef MFMA16
#undef PHASE
#undef VM8
#undef VM4
#undef VM0
#undef NOSTG
#undef NOVM
#undef NOPREF
#undef TILE_FULL
}

// ---------------- y[b] = sum_d out[b][d]*Wlast[d] + blast  (one wave per row) -----------
__global__ __launch_bounds__(256) void last_k(const u16* __restrict__ out,
                                              const float* __restrict__ wlast,
                                              const float* __restrict__ blast,
                                              float* __restrict__ y) {
    int gw = (blockIdx.x * 256 + threadIdx.x) >> 6;
    int lane = threadIdx.x & 63;
    if (gw >= BROWS) return;
    const u16* orow = out + (size_t)gw * DDIM;
    float s = 0.0f;
#pragma unroll
    for (int it = 0; it < 4; ++it) {
        int k = it * 256 + lane * 4;
        u16x4 o = *(const u16x4*)(orow + k);
        f32x4 w = *(const f32x4*)(wlast + k);
        s += bf2f(o.x) * w.x + bf2f(o.y) * w.y + bf2f(o.z) * w.z + bf2f(o.w) * w.w;
    }
#pragma unroll
    for (int off = 32; off > 0; off >>= 1) s += __shfl_down(s, off, 64);
    if (lane == 0) y[gw] = s + blast[0];
}

extern "C" void kernel_launch(void* const* d_in, const int* in_sizes, int n_in,
                              void* d_out, int out_size, void* d_ws, size_t ws_size,
                              hipStream_t stream) {
    const float* x     = (const float*)d_in[0];  // [32768,100]
    const float* W0    = (const float*)d_in[1];  // [1024,100]
    const float* b0    = (const float*)d_in[2];  // [1024]
    const float* Ws    = (const float*)d_in[3];  // [5,1024,1024]
    const float* bs    = (const float*)d_in[4];  // [5,1024]
    const float* bw    = (const float*)d_in[5];  // [5,1024]
    const float* Wlast = (const float*)d_in[6];  // [1,1024]
    const float* blast = (const float*)d_in[7];  // [1]
    const float* noise = (const float*)d_in[8];  // [5,32768,1024]
    float* y = (float*)d_out;                    // [32768]
    (void)in_sizes; (void)n_in; (void)out_size; (void)ws_size;

    char* ws = (char*)d_ws;
    size_t off = 0;
    auto alloc = [&](size_t bytes) {
        char* p = ws + off;
        off += (bytes + 255) & ~(size_t)255;
        return p;
    };
    u16* outB0 = (u16*)alloc((size_t)BROWS * DDIM * 2);       // 64 MB
    u16* outB1 = (u16*)alloc((size_t)BROWS * DDIM * 2);       // 64 MB
    u16* xb    = (u16*)alloc((size_t)BROWS * 128 * 2);        // 8 MB
    u16* W0b   = (u16*)alloc((size_t)DDIM * 128 * 2);         // 256 KB
    u16* Wsb   = (u16*)alloc((size_t)NBLK * DDIM * DDIM * 2); // 10 MB
    float* zw  = (float*)alloc((size_t)NBLK * BROWS * 4);     // 640 KB

    // convert inputs to bf16 (x, W0 padded K 100->128)
    pad_cvt<<<(BROWS * 128 + 255) / 256, 256, 0, stream>>>(x, xb, BROWS, 100, 128);
    pad_cvt<<<(DDIM * 128 + 255) / 256, 256, 0, stream>>>(W0, W0b, DDIM, 100, 128);
    pad_cvt<<<(NBLK * DDIM * DDIM + 255) / 256, 256, 0, stream>>>(Ws, Wsb, NBLK * DDIM, DDIM, DDIM);

    // zw[i][b] = noise_i[b] . bw_i   (the ONLY read of noise)
    zw_kernel<<<(NBLK * BROWS) / 4, 256, 0, stream>>>(noise, bw, zw);

    // first layer: out0 = tanh(x @ W0^T + b0)
    gemm256<128, 0><<<512, 512, 0, stream>>>(xb, W0b, b0, outB0,
                                             nullptr, nullptr, nullptr);

    // 5 residual blocks (ping-pong out buffers)
    u16* cur = outB0;
    u16* nxt = outB1;
    for (int i = 0; i < NBLK; ++i) {
        gemm256<1024, 1><<<512, 512, 0, stream>>>(
            cur, Wsb + (size_t)i * DDIM * DDIM, bs + (size_t)i * DDIM, nxt, cur,
            zw + (size_t)i * BROWS, bw + (size_t)i * DDIM);
        u16* t = cur; cur = nxt; nxt = t;
    }

    // y = out @ Wlast^T + blast
    last_k<<<BROWS / 4, 256, 0, stream>>>(cur, Wlast, blast, y);
}

// Round 6
// 613.765 us; speedup vs baseline: 1.4526x; 1.4526x over previous
//
#include <hip/hip_runtime.h>
#include <hip/hip_bf16.h>

// SDEnet R6: 256x256 GEMM, 2 phases per K-tile (BK=64), k-half LDS regions (R3 dataflow),
// self-contained phases (no cross-phase frag carry), counted vmcnt(4)/tile, setprio MFMA
// clusters of 32. T1 XCD swizzle + conflict-free chunk-XOR LDS swizzle. Noise read once.

typedef unsigned short u16;
typedef __attribute__((ext_vector_type(8))) short short8;
typedef __attribute__((ext_vector_type(8))) u16 u16x8;
typedef __attribute__((ext_vector_type(4))) u16 u16x4;
typedef __attribute__((ext_vector_type(4))) float f32x4;

#define BROWS 32768
#define DDIM 1024
#define NBLK 5
#define H_STEP 0.1f
#define SQRT_H 0.31622776601683794f

#define FENCE() asm volatile("" ::: "memory")
#define BARRIER() do { FENCE(); __builtin_amdgcn_s_barrier(); FENCE(); } while (0)

__device__ __forceinline__ float bf2f(u16 u) {
    return __uint_as_float(((unsigned)u) << 16);
}
__device__ __forceinline__ u16 f2bf(float f) {
    unsigned u = __float_as_uint(f);
    unsigned r = 0x7fffu + ((u >> 16) & 1u);
    return (u16)((u + r) >> 16);
}
__device__ __forceinline__ float fast_tanh(float s) {
    float e = __expf(2.0f * s);
    return 1.0f - 2.0f * __builtin_amdgcn_rcpf(e + 1.0f);
}

// async global -> LDS, 16B per lane, wave-uniform LDS base + lane*16
#define GLOAD_LDS16(g, l)                                                        \
    __builtin_amdgcn_global_load_lds(                                            \
        (const __attribute__((address_space(1))) unsigned int*)(const void*)(g), \
        (__attribute__((address_space(3))) unsigned int*)(void*)(l), 16, 0, 0)

// ---------------- pad/convert fp32 -> bf16 (optionally zero-padded cols) ----------------
__global__ __launch_bounds__(256) void pad_cvt(const float* __restrict__ src,
                                               u16* __restrict__ dst,
                                               int R, int C, int Cp) {
    int idx = blockIdx.x * 256 + threadIdx.x;
    if (idx >= R * Cp) return;
    int r = idx / Cp;
    int c = idx - r * Cp;
    float v = (c < C) ? src[(size_t)r * C + c] : 0.0f;
    dst[idx] = f2bf(v);
}

// ---------------- zw[i][b] = sum_d noise[i][b][d] * bw[i][d]  (one wave per row) --------
__global__ __launch_bounds__(256) void zw_kernel(const float* __restrict__ noise,
                                                 const float* __restrict__ bw,
                                                 float* __restrict__ zw) {
    int gw = (blockIdx.x * 256 + threadIdx.x) >> 6;
    int lane = threadIdx.x & 63;
    if (gw >= NBLK * BROWS) return;
    int i = gw >> 15;
    const float* zr = noise + (size_t)gw * DDIM;
    const float* wr = bw + i * DDIM;
    float s = 0.0f;
#pragma unroll
    for (int it = 0; it < 4; ++it) {
        int k = it * 256 + lane * 4;
        f32x4 z = *(const f32x4*)(zr + k);
        f32x4 w = *(const f32x4*)(wr + k);
        s += z.x * w.x + z.y * w.y + z.z * w.z + z.w * w.w;
    }
#pragma unroll
    for (int off = 32; off > 0; off >>= 1) s += __shfl_down(s, off, 64);
    if (lane == 0) zw[gw] = s;
}

// ---------------- 256^2 GEMM, 2 phases/K-tile: C = A[M][KK] @ B[1024][KK]^T -------------
// LDS per buf(65536B): A:[kh(16384)][row256][k32 bf16], B at +32768 same. 2 bufs = 128 KiB.
// Chunk swizzle (both sides): physical 16B-chunk = logical ^ ((row>>1)&3).
template <int KK, int EPI>
__global__ __launch_bounds__(512, 2) void gemm256(const u16* __restrict__ Ag,
                                                  const u16* __restrict__ Bg,
                                                  const float* __restrict__ bias,
                                                  u16* __restrict__ outW,
                                                  const u16* __restrict__ outR,
                                                  const float* __restrict__ zw,
                                                  const float* __restrict__ bwv) {
    constexpr int NT = KK / 64;
    static_assert(NT >= 2 && (NT & 1) == 0, "NT even, >=2");
    __shared__ __align__(16) u16 smem[65536];  // 128 KiB
    char* lds = (char*)smem;

    const int bid = blockIdx.x;                 // 512 blocks, 512 % 8 == 0
    const int swz = (bid & 7) * 64 + (bid >> 3);
    const int row0 = (swz >> 2) * 256;
    const int col0 = (swz & 3) * 256;

    const int tid = threadIdx.x;
    const int lane = tid & 63;
    const int wid = tid >> 6;
    const int wm = wid >> 2;   // 2 row-waves
    const int wn = wid & 3;    // 4 col-waves

    // ---- staging: thread covers row (tid>>2)(+128), logical chunk (tid&3), pre-swizzled
    const int srow = tid >> 2;
    const int skq = (tid & 3) ^ ((tid >> 3) & 3);   // ^((row>>1)&3)
    const u16* agp0 = Ag + (size_t)(row0 + srow) * KK + skq * 8;
    const u16* agp1 = Ag + (size_t)(row0 + 128 + srow) * KK + skq * 8;
    const u16* bgp0 = Bg + (size_t)(col0 + srow) * KK + skq * 8;
    const u16* bgp1 = Bg + (size_t)(col0 + 128 + srow) * KK + skq * 8;
    char* lp0 = lds + wid * 1024;  // wave-uniform LDS base (+lane*16 by HW)

    // stage half q: 0=A-kh0, 1=B-kh0, 2=A-kh1, 3=B-kh1 of tile t -> buf[t&1] (2 gloads)
    auto stage = [&](int t, int q) {
        const int is_b = q & 1;
        const int kh = q >> 1;
        const int koff = t * 64 + kh * 32;
        char* dst = lp0 + ((t & 1) << 16) + (is_b << 15) + (kh << 14);
        const u16* g0 = (is_b ? bgp0 : agp0) + koff;
        const u16* g1 = (is_b ? bgp1 : agp1) + koff;
        GLOAD_LDS16(g0, dst);
        GLOAD_LDS16(g1, dst + 8192);
    };

    // ---- frag-read bases: logical chunk = lane>>4, row ~ lane&15 -> phys ^ ((lane>>1)&3)
    const int rchunk = ((lane >> 4) ^ ((lane >> 1) & 3)) << 4;
    const int aoffL = (wm * 128 + (lane & 15)) * 64 + rchunk;          // + m*1024 + kh*16384 + buf*65536
    const int boffL = 32768 + (wn * 64 + (lane & 15)) * 64 + rchunk;   // + n*1024 + ...

    short8 af[8], bf[4];
    f32x4 acc[8][4];
#pragma unroll
    for (int m = 0; m < 8; ++m)
#pragma unroll
        for (int n = 0; n < 4; ++n) acc[m][n] = (f32x4){0.f, 0.f, 0.f, 0.f};

#define RD(off) (*(const short8*)(lds + (off)))
// phase: read ALL 12 frags of k-half kh, issue 2 stage-halves, barrier, 32-MFMA cluster.
#define PHASE2(kh, bufc, STG1, STG2, VMW)                                             \
    do {                                                                              \
        const int rb = (bufc) * 65536 + (kh) * 16384;                                 \
        _Pragma("unroll") for (int m = 0; m < 8; ++m)                                 \
            af[m] = RD(rb + aoffL + m * 1024);                                        \
        _Pragma("unroll") for (int n = 0; n < 4; ++n)                                 \
            bf[n] = RD(rb + boffL + n * 1024);                                        \
        STG1;                                                                         \
        STG2;                                                                         \
        FENCE(); __builtin_amdgcn_s_barrier();                                        \
        asm volatile("s_waitcnt lgkmcnt(0)" ::: "memory");                            \
        __builtin_amdgcn_s_setprio(1);                                                \
        _Pragma("unroll") for (int m = 0; m < 8; ++m)                                 \
            _Pragma("unroll") for (int n = 0; n < 4; ++n)                             \
                acc[m][n] = __builtin_amdgcn_mfma_f32_16x16x32_bf16(af[m], bf[n], acc[m][n], 0, 0, 0); \
        __builtin_amdgcn_s_setprio(0);                                                \
        VMW;                                                                          \
        FENCE(); __builtin_amdgcn_s_barrier(); FENCE();                               \
    } while (0)
#define VM4 asm volatile("s_waitcnt vmcnt(4)" ::: "memory")
#define VM0 asm volatile("s_waitcnt vmcnt(0)" ::: "memory")
#define NOSTG ((void)0)
#define NOVM ((void)0)

// tile t (buf c): ph0 reads kh0 + stages (t+1,kh1 halves); ph1 reads kh1 + stages
// (t+2,kh0 halves) + vmcnt(4) -> (t+1,*) all landed, only (t+2,kh0) pair outstanding.
#define TILE2(t, c)                                                                   \
    do {                                                                              \
        PHASE2(0, c, stage((t) + 1, 2), stage((t) + 1, 3), NOVM);                     \
        PHASE2(1, c, stage((t) + 2, 0), stage((t) + 2, 1), VM4);                      \
    } while (0)

    // ---- prologue: tile0 all 4 halves + tile1 kh0 halves (12 loads) ----
    stage(0, 0); stage(0, 1); stage(0, 2); stage(0, 3);
    stage(1, 0); stage(1, 1);
    asm volatile("s_waitcnt vmcnt(4)" ::: "memory");  // tile0 fully landed
    BARRIER();

    for (int t2 = 0; t2 < NT / 2 - 1; ++t2) {
        TILE2(2 * t2, 0);
        TILE2(2 * t2 + 1, 1);
    }
    // ---- peeled tile NT-2 (buf 0): stage only (NT-1) kh1 halves, then drain ----
    PHASE2(0, 0, stage(NT - 1, 2), stage(NT - 1, 3), NOVM);
    PHASE2(1, 0, NOSTG, NOSTG, VM0);
    // ---- peeled tile NT-1 (buf 1): no stages ----
    PHASE2(0, 1, NOSTG, NOSTG, NOVM);
    PHASE2(1, 1, NOSTG, NOSTG, NOVM);

    // ---- epilogue: all LDS reads drained (consumed pre-barrier) + final barrier ----
    float bcol[4];
#pragma unroll
    for (int ng = 0; ng < 4; ++ng) bcol[ng] = bias[col0 + wn * 64 + ng * 16 + (lane & 15)];

    char* wbase = lds + wid * 16384;  // wave-private 128x64 bf16 delta tile
    const int lr0 = (lane >> 4) * 4;
    const int lc0 = lane & 15;
#pragma unroll
    for (int m = 0; m < 8; ++m) {
#pragma unroll
        for (int ng = 0; ng < 4; ++ng) {
#pragma unroll
            for (int j = 0; j < 4; ++j) {
                int lrow = m * 16 + lr0 + j;
                int lcol = ng * 16 + lc0;
                float t = fast_tanh(acc[m][ng][j] + bcol[ng]);
                float d = (EPI == 0) ? t : H_STEP * t;
                int chunk = (lcol >> 3) ^ ((lrow >> 2) & 7);
                *(u16*)(wbase + lrow * 128 + (chunk << 4) + (lcol & 7) * 2) = f2bf(d);
            }
        }
    }

    const int gr_base = row0 + wm * 128;
    const int gc_base = col0 + wn * 64;
#pragma unroll
    for (int it = 0; it < 16; ++it) {
        int lrow = it * 8 + (lane >> 3);
        int chunk = lane & 7;
        int schunk = chunk ^ ((lrow >> 2) & 7);
        u16x8 d8 = *(const u16x8*)(wbase + lrow * 128 + (schunk << 4));
        int grow = gr_base + lrow;
        int gcol = gc_base + chunk * 8;
        size_t gidx = (size_t)grow * DDIM + gcol;
        u16x8 o8;
        if constexpr (EPI == 0) {
            o8 = d8;
        } else {
            u16x8 old8 = *(const u16x8*)(outR + gidx);
            float zr = SQRT_H * zw[grow];
            f32x4 bw0 = *(const f32x4*)(bwv + gcol);
            f32x4 bw1 = *(const f32x4*)(bwv + gcol + 4);
#pragma unroll
            for (int e = 0; e < 8; ++e) {
                float bwe = (e < 4) ? bw0[e] : bw1[e - 4];
                float v = bf2f(old8[e]) + bf2f(d8[e]) + zr * bwe;
                o8[e] = f2bf(v);
            }
        }
        *(u16x8*)(outW + gidx) = o8;
    }
#undef RD
#undef PHASE2
#undef VM4
#undef VM0
#undef NOSTG
#undef NOVM
#undef TILE2
}

// ---------------- y[b] = sum_d out[b][d]*Wlast[d] + blast  (one wave per row) -----------
__global__ __launch_bounds__(256) void last_k(const u16* __restrict__ out,
                                              const float* __restrict__ wlast,
                                              const float* __restrict__ blast,
                                              float* __restrict__ y) {
    int gw = (blockIdx.x * 256 + threadIdx.x) >> 6;
    int lane = threadIdx.x & 63;
    if (gw >= BROWS) return;
    const u16* orow = out + (size_t)gw * DDIM;
    float s = 0.0f;
#pragma unroll
    for (int it = 0; it < 4; ++it) {
        int k = it * 256 + lane * 4;
        u16x4 o = *(const u16x4*)(orow + k);
        f32x4 w = *(const f32x4*)(wlast + k);
        s += bf2f(o.x) * w.x + bf2f(o.y) * w.y + bf2f(o.z) * w.z + bf2f(o.w) * w.w;
    }
#pragma unroll
    for (int off = 32; off > 0; off >>= 1) s += __shfl_down(s, off, 64);
    if (lane == 0) y[gw] = s + blast[0];
}

extern "C" void kernel_launch(void* const* d_in, const int* in_sizes, int n_in,
                              void* d_out, int out_size, void* d_ws, size_t ws_size,
                              hipStream_t stream) {
    const float* x     = (const float*)d_in[0];  // [32768,100]
    const float* W0    = (const float*)d_in[1];  // [1024,100]
    const float* b0    = (const float*)d_in[2];  // [1024]
    const float* Ws    = (const float*)d_in[3];  // [5,1024,1024]
    const float* bs    = (const float*)d_in[4];  // [5,1024]
    const float* bw    = (const float*)d_in[5];  // [5,1024]
    const float* Wlast = (const float*)d_in[6];  // [1,1024]
    const float* blast = (const float*)d_in[7];  // [1]
    const float* noise = (const float*)d_in[8];  // [5,32768,1024]
    float* y = (float*)d_out;                    // [32768]
    (void)in_sizes; (void)n_in; (void)out_size; (void)ws_size;

    char* ws = (char*)d_ws;
    size_t off = 0;
    auto alloc = [&](size_t bytes) {
        char* p = ws + off;
        off += (bytes + 255) & ~(size_t)255;
        return p;
    };
    u16* outB0 = (u16*)alloc((size_t)BROWS * DDIM * 2);       // 64 MB
    u16* outB1 = (u16*)alloc((size_t)BROWS * DDIM * 2);       // 64 MB
    u16* xb    = (u16*)alloc((size_t)BROWS * 128 * 2);        // 8 MB
    u16* W0b   = (u16*)alloc((size_t)DDIM * 128 * 2);         // 256 KB
    u16* Wsb   = (u16*)alloc((size_t)NBLK * DDIM * DDIM * 2); // 10 MB
    float* zw  = (float*)alloc((size_t)NBLK * BROWS * 4);     // 640 KB

    // convert inputs to bf16 (x, W0 padded K 100->128)
    pad_cvt<<<(BROWS * 128 + 255) / 256, 256, 0, stream>>>(x, xb, BROWS, 100, 128);
    pad_cvt<<<(DDIM * 128 + 255) / 256, 256, 0, stream>>>(W0, W0b, DDIM, 100, 128);
    pad_cvt<<<(NBLK * DDIM * DDIM + 255) / 256, 256, 0, stream>>>(Ws, Wsb, NBLK * DDIM, DDIM, DDIM);

    // zw[i][b] = noise_i[b] . bw_i   (the ONLY read of noise)
    zw_kernel<<<(NBLK * BROWS) / 4, 256, 0, stream>>>(noise, bw, zw);

    // first layer: out0 = tanh(x @ W0^T + b0)
    gemm256<128, 0><<<512, 512, 0, stream>>>(xb, W0b, b0, outB0,
                                             nullptr, nullptr, nullptr);

    // 5 residual blocks (ping-pong out buffers)
    u16* cur = outB0;
    u16* nxt = outB1;
    for (int i = 0; i < NBLK; ++i) {
        gemm256<1024, 1><<<512, 512, 0, stream>>>(
            cur, Wsb + (size_t)i * DDIM * DDIM, bs + (size_t)i * DDIM, nxt, cur,
            zw + (size_t)i * BROWS, bw + (size_t)i * DDIM);
        u16* t = cur; cur = nxt; nxt = t;
    }

    // y = out @ Wlast^T + blast
    last_k<<<BROWS / 4, 256, 0, stream>>>(cur, Wlast, blast, y);
}

// Round 7
// 605.819 us; speedup vs baseline: 1.4717x; 1.0131x over previous
//
#include <hip/hip_runtime.h>
#include <hip/hip_bf16.h>

// SDEnet R7: 256x256 GEMM, 2 phases/K-tile. Frag reads moved AFTER the opening barrier
// into the MFMA region (no explicit lgkmcnt(0)) -> compiler emits counted lgkm and
// interleaves ds_read with MFMA. Counted vmcnt before opening barrier. Noise read once.

typedef unsigned short u16;
typedef __attribute__((ext_vector_type(8))) short short8;
typedef __attribute__((ext_vector_type(8))) u16 u16x8;
typedef __attribute__((ext_vector_type(4))) u16 u16x4;
typedef __attribute__((ext_vector_type(4))) float f32x4;

#define BROWS 32768
#define DDIM 1024
#define NBLK 5
#define H_STEP 0.1f
#define SQRT_H 0.31622776601683794f

#define FENCE() asm volatile("" ::: "memory")
#define BARRIER() do { FENCE(); __builtin_amdgcn_s_barrier(); FENCE(); } while (0)

__device__ __forceinline__ float bf2f(u16 u) {
    return __uint_as_float(((unsigned)u) << 16);
}
__device__ __forceinline__ u16 f2bf(float f) {
    unsigned u = __float_as_uint(f);
    unsigned r = 0x7fffu + ((u >> 16) & 1u);
    return (u16)((u + r) >> 16);
}
__device__ __forceinline__ float fast_tanh(float s) {
    float e = __expf(2.0f * s);
    return 1.0f - 2.0f * __builtin_amdgcn_rcpf(e + 1.0f);
}

// async global -> LDS, 16B per lane, wave-uniform LDS base + lane*16
#define GLOAD_LDS16(g, l)                                                        \
    __builtin_amdgcn_global_load_lds(                                            \
        (const __attribute__((address_space(1))) unsigned int*)(const void*)(g), \
        (__attribute__((address_space(3))) unsigned int*)(void*)(l), 16, 0, 0)

// ---------------- pad/convert fp32 -> bf16 (optionally zero-padded cols) ----------------
__global__ __launch_bounds__(256) void pad_cvt(const float* __restrict__ src,
                                               u16* __restrict__ dst,
                                               int R, int C, int Cp) {
    int idx = blockIdx.x * 256 + threadIdx.x;
    if (idx >= R * Cp) return;
    int r = idx / Cp;
    int c = idx - r * Cp;
    float v = (c < C) ? src[(size_t)r * C + c] : 0.0f;
    dst[idx] = f2bf(v);
}

// ---------------- zw[i][b] = sum_d noise[i][b][d] * bw[i][d]  (one wave per row) --------
__global__ __launch_bounds__(256) void zw_kernel(const float* __restrict__ noise,
                                                 const float* __restrict__ bw,
                                                 float* __restrict__ zw) {
    int gw = (blockIdx.x * 256 + threadIdx.x) >> 6;
    int lane = threadIdx.x & 63;
    if (gw >= NBLK * BROWS) return;
    int i = gw >> 15;
    const float* zr = noise + (size_t)gw * DDIM;
    const float* wr = bw + i * DDIM;
    float s = 0.0f;
#pragma unroll
    for (int it = 0; it < 4; ++it) {
        int k = it * 256 + lane * 4;
        f32x4 z = *(const f32x4*)(zr + k);
        f32x4 w = *(const f32x4*)(wr + k);
        s += z.x * w.x + z.y * w.y + z.z * w.z + z.w * w.w;
    }
#pragma unroll
    for (int off = 32; off > 0; off >>= 1) s += __shfl_down(s, off, 64);
    if (lane == 0) zw[gw] = s;
}

// ---------------- 256^2 GEMM, 2 phases/K-tile: C = A[M][KK] @ B[1024][KK]^T -------------
// LDS per buf(65536B): A:[kh(16384)][row256][k32 bf16], B at +32768 same. 2 bufs = 128 KiB.
// Chunk swizzle (both sides): physical 16B-chunk = logical ^ ((row>>1)&3).
template <int KK, int EPI>
__global__ __launch_bounds__(512, 2) void gemm256(const u16* __restrict__ Ag,
                                                  const u16* __restrict__ Bg,
                                                  const float* __restrict__ bias,
                                                  u16* __restrict__ outW,
                                                  const u16* __restrict__ outR,
                                                  const float* __restrict__ zw,
                                                  const float* __restrict__ bwv) {
    constexpr int NT = KK / 64;
    static_assert(NT >= 2 && (NT & 1) == 0, "NT even, >=2");
    __shared__ __align__(16) u16 smem[65536];  // 128 KiB
    char* lds = (char*)smem;

    const int bid = blockIdx.x;                 // 512 blocks, 512 % 8 == 0
    const int swz = (bid & 7) * 64 + (bid >> 3);
    const int row0 = (swz >> 2) * 256;
    const int col0 = (swz & 3) * 256;

    const int tid = threadIdx.x;
    const int lane = tid & 63;
    const int wid = tid >> 6;
    const int wm = wid >> 2;   // 2 row-waves
    const int wn = wid & 3;    // 4 col-waves

    // ---- staging: thread covers row (tid>>2)(+128), logical chunk (tid&3), pre-swizzled
    const int srow = tid >> 2;
    const int skq = (tid & 3) ^ ((tid >> 3) & 3);   // ^((row>>1)&3)
    const u16* agp0 = Ag + (size_t)(row0 + srow) * KK + skq * 8;
    const u16* agp1 = Ag + (size_t)(row0 + 128 + srow) * KK + skq * 8;
    const u16* bgp0 = Bg + (size_t)(col0 + srow) * KK + skq * 8;
    const u16* bgp1 = Bg + (size_t)(col0 + 128 + srow) * KK + skq * 8;
    char* lp0 = lds + wid * 1024;  // wave-uniform LDS base (+lane*16 by HW)

    // stage half q: 0=A-kh0, 1=B-kh0, 2=A-kh1, 3=B-kh1 of tile t -> buf[t&1] (2 gloads)
    auto stage = [&](int t, int q) {
        const int is_b = q & 1;
        const int kh = q >> 1;
        const int koff = t * 64 + kh * 32;
        char* dst = lp0 + ((t & 1) << 16) + (is_b << 15) + (kh << 14);
        const u16* g0 = (is_b ? bgp0 : agp0) + koff;
        const u16* g1 = (is_b ? bgp1 : agp1) + koff;
        GLOAD_LDS16(g0, dst);
        GLOAD_LDS16(g1, dst + 8192);
    };

    // ---- frag-read bases: logical chunk = lane>>4, row ~ lane&15 -> phys ^ ((lane>>1)&3)
    const int rchunk = ((lane >> 4) ^ ((lane >> 1) & 3)) << 4;
    const int aoffL = (wm * 128 + (lane & 15)) * 64 + rchunk;          // + m*1024 + kh*16384 + buf*65536
    const int boffL = 32768 + (wn * 64 + (lane & 15)) * 64 + rchunk;   // + n*1024 + ...

    short8 af[8], bf[4];
    f32x4 acc[8][4];
#pragma unroll
    for (int m = 0; m < 8; ++m)
#pragma unroll
        for (int n = 0; n < 4; ++n) acc[m][n] = (f32x4){0.f, 0.f, 0.f, 0.f};

#define RD(off) (*(const short8*)(lds + (off)))
// phase: issue stages, counted vm-wait, barrier, then {12 frag reads + 32 MFMA} in ONE
// scheduling region -> compiler interleaves with counted lgkmcnt (no drain).
#define PHASE2(kh, bufc, STG1, STG2, VMW)                                             \
    do {                                                                              \
        STG1;                                                                         \
        STG2;                                                                         \
        VMW;                                                                          \
        FENCE(); __builtin_amdgcn_s_barrier(); FENCE();                               \
        __builtin_amdgcn_s_setprio(1);                                                \
        const int rb = (bufc) * 65536 + (kh) * 16384;                                 \
        _Pragma("unroll") for (int m = 0; m < 8; ++m)                                 \
            af[m] = RD(rb + aoffL + m * 1024);                                        \
        _Pragma("unroll") for (int n = 0; n < 4; ++n)                                 \
            bf[n] = RD(rb + boffL + n * 1024);                                        \
        _Pragma("unroll") for (int m = 0; m < 8; ++m)                                 \
            _Pragma("unroll") for (int n = 0; n < 4; ++n)                             \
                acc[m][n] = __builtin_amdgcn_mfma_f32_16x16x32_bf16(af[m], bf[n], acc[m][n], 0, 0, 0); \
        __builtin_amdgcn_s_setprio(0);                                                \
        FENCE(); __builtin_amdgcn_s_barrier(); FENCE();                               \
    } while (0)
#define VM4 asm volatile("s_waitcnt vmcnt(4)" ::: "memory")
#define VM0 asm volatile("s_waitcnt vmcnt(0)" ::: "memory")
#define NOSTG ((void)0)
#define NOVM ((void)0)

// tile t (buf c): ph0 stages (t+1) kh1 halves; ph1 stages (t+2) kh0 halves + VM4 before
// its opening barrier -> outstanding = (t+2,kh0) pair only; everything older landed.
#define TILE2(t, c)                                                                   \
    do {                                                                              \
        PHASE2(0, c, stage((t) + 1, 2), stage((t) + 1, 3), NOVM);                     \
        PHASE2(1, c, stage((t) + 2, 0), stage((t) + 2, 1), VM4);                      \
    } while (0)

    // ---- prologue: tile0 all 4 halves + tile1 kh0 halves (12 loads) ----
    stage(0, 0); stage(0, 1); stage(0, 2); stage(0, 3);
    stage(1, 0); stage(1, 1);
    asm volatile("s_waitcnt vmcnt(4)" ::: "memory");  // tile0 fully landed
    BARRIER();

    for (int t2 = 0; t2 < NT / 2 - 1; ++t2) {
        TILE2(2 * t2, 0);
        TILE2(2 * t2 + 1, 1);
    }
    // ---- peeled tile NT-2 (buf 0): stage only (NT-1) kh1 halves, then drain ----
    PHASE2(0, 0, stage(NT - 1, 2), stage(NT - 1, 3), NOVM);
    PHASE2(1, 0, NOSTG, NOSTG, VM0);
    // ---- peeled tile NT-1 (buf 1): no stages ----
    PHASE2(0, 1, NOSTG, NOSTG, NOVM);
    PHASE2(1, 1, NOSTG, NOSTG, NOVM);

    // ---- epilogue: final barrier passed; LDS reuse is wave-private from here ----
    float bcol[4];
#pragma unroll
    for (int ng = 0; ng < 4; ++ng) bcol[ng] = bias[col0 + wn * 64 + ng * 16 + (lane & 15)];

    char* wbase = lds + wid * 16384;  // wave-private 128x64 bf16 delta tile
    const int lr0 = (lane >> 4) * 4;
    const int lc0 = lane & 15;
#pragma unroll
    for (int m = 0; m < 8; ++m) {
#pragma unroll
        for (int ng = 0; ng < 4; ++ng) {
#pragma unroll
            for (int j = 0; j < 4; ++j) {
                int lrow = m * 16 + lr0 + j;
                int lcol = ng * 16 + lc0;
                float t = fast_tanh(acc[m][ng][j] + bcol[ng]);
                float d = (EPI == 0) ? t : H_STEP * t;
                int chunk = (lcol >> 3) ^ ((lrow >> 2) & 7);
                *(u16*)(wbase + lrow * 128 + (chunk << 4) + (lcol & 7) * 2) = f2bf(d);
            }
        }
    }

    const int gr_base = row0 + wm * 128;
    const int gc_base = col0 + wn * 64;
#pragma unroll
    for (int it = 0; it < 16; ++it) {
        int lrow = it * 8 + (lane >> 3);
        int chunk = lane & 7;
        int schunk = chunk ^ ((lrow >> 2) & 7);
        u16x8 d8 = *(const u16x8*)(wbase + lrow * 128 + (schunk << 4));
        int grow = gr_base + lrow;
        int gcol = gc_base + chunk * 8;
        size_t gidx = (size_t)grow * DDIM + gcol;
        u16x8 o8;
        if constexpr (EPI == 0) {
            o8 = d8;
        } else {
            u16x8 old8 = *(const u16x8*)(outR + gidx);
            float zr = SQRT_H * zw[grow];
            f32x4 bw0 = *(const f32x4*)(bwv + gcol);
            f32x4 bw1 = *(const f32x4*)(bwv + gcol + 4);
#pragma unroll
            for (int e = 0; e < 8; ++e) {
                float bwe = (e < 4) ? bw0[e] : bw1[e - 4];
                float v = bf2f(old8[e]) + bf2f(d8[e]) + zr * bwe;
                o8[e] = f2bf(v);
            }
        }
        *(u16x8*)(outW + gidx) = o8;
    }
#undef RD
#undef PHASE2
#undef VM4
#undef VM0
#undef NOSTG
#undef NOVM
#undef TILE2
}

// ---------------- y[b] = sum_d out[b][d]*Wlast[d] + blast  (one wave per row) -----------
__global__ __launch_bounds__(256) void last_k(const u16* __restrict__ out,
                                              const float* __restrict__ wlast,
                                              const float* __restrict__ blast,
                                              float* __restrict__ y) {
    int gw = (blockIdx.x * 256 + threadIdx.x) >> 6;
    int lane = threadIdx.x & 63;
    if (gw >= BROWS) return;
    const u16* orow = out + (size_t)gw * DDIM;
    float s = 0.0f;
#pragma unroll
    for (int it = 0; it < 4; ++it) {
        int k = it * 256 + lane * 4;
        u16x4 o = *(const u16x4*)(orow + k);
        f32x4 w = *(const f32x4*)(wlast + k);
        s += bf2f(o.x) * w.x + bf2f(o.y) * w.y + bf2f(o.z) * w.z + bf2f(o.w) * w.w;
    }
#pragma unroll
    for (int off = 32; off > 0; off >>= 1) s += __shfl_down(s, off, 64);
    if (lane == 0) y[gw] = s + blast[0];
}

extern "C" void kernel_launch(void* const* d_in, const int* in_sizes, int n_in,
                              void* d_out, int out_size, void* d_ws, size_t ws_size,
                              hipStream_t stream) {
    const float* x     = (const float*)d_in[0];  // [32768,100]
    const float* W0    = (const float*)d_in[1];  // [1024,100]
    const float* b0    = (const float*)d_in[2];  // [1024]
    const float* Ws    = (const float*)d_in[3];  // [5,1024,1024]
    const float* bs    = (const float*)d_in[4];  // [5,1024]
    const float* bw    = (const float*)d_in[5];  // [5,1024]
    const float* Wlast = (const float*)d_in[6];  // [1,1024]
    const float* blast = (const float*)d_in[7];  // [1]
    const float* noise = (const float*)d_in[8];  // [5,32768,1024]
    float* y = (float*)d_out;                    // [32768]
    (void)in_sizes; (void)n_in; (void)out_size; (void)ws_size;

    char* ws = (char*)d_ws;
    size_t off = 0;
    auto alloc = [&](size_t bytes) {
        char* p = ws + off;
        off += (bytes + 255) & ~(size_t)255;
        return p;
    };
    u16* outB0 = (u16*)alloc((size_t)BROWS * DDIM * 2);       // 64 MB
    u16* outB1 = (u16*)alloc((size_t)BROWS * DDIM * 2);       // 64 MB
    u16* xb    = (u16*)alloc((size_t)BROWS * 128 * 2);        // 8 MB
    u16* W0b   = (u16*)alloc((size_t)DDIM * 128 * 2);         // 256 KB
    u16* Wsb   = (u16*)alloc((size_t)NBLK * DDIM * DDIM * 2); // 10 MB
    float* zw  = (float*)alloc((size_t)NBLK * BROWS * 4);     // 640 KB

    // convert inputs to bf16 (x, W0 padded K 100->128)
    pad_cvt<<<(BROWS * 128 + 255) / 256, 256, 0, stream>>>(x, xb, BROWS, 100, 128);
    pad_cvt<<<(DDIM * 128 + 255) / 256, 256, 0, stream>>>(W0, W0b, DDIM, 100, 128);
    pad_cvt<<<(NBLK * DDIM * DDIM + 255) / 256, 256, 0, stream>>>(Ws, Wsb, NBLK * DDIM, DDIM, DDIM);

    // zw[i][b] = noise_i[b] . bw_i   (the ONLY read of noise)
    zw_kernel<<<(NBLK * BROWS) / 4, 256, 0, stream>>>(noise, bw, zw);

    // first layer: out0 = tanh(x @ W0^T + b0)
    gemm256<128, 0><<<512, 512, 0, stream>>>(xb, W0b, b0, outB0,
                                             nullptr, nullptr, nullptr);

    // 5 residual blocks (ping-pong out buffers)
    u16* cur = outB0;
    u16* nxt = outB1;
    for (int i = 0; i < NBLK; ++i) {
        gemm256<1024, 1><<<512, 512, 0, stream>>>(
            cur, Wsb + (size_t)i * DDIM * DDIM, bs + (size_t)i * DDIM, nxt, cur,
            zw + (size_t)i * BROWS, bw + (size_t)i * DDIM);
        u16* t = cur; cur = nxt; nxt = t;
    }

    // y = out @ Wlast^T + blast
    last_k<<<BROWS / 4, 256, 0, stream>>>(cur, Wlast, blast, y);
}